// Round 2
// baseline (490.306 us; speedup 1.0000x reference)
//
#include <hip/hip_runtime.h>

// NCM via bf16-split MFMA — wave-independent restructure.
// Each wave owns 16 batch elements and ALL 64 features of every layer:
// zero __syncthreads in the main loop (all LDS producer->consumer traffic is
// intra-wave; waves drift freely and hide each other's latency).
// MFMA operands are SWAPPED vs the cooperative version: D = W·X^T = [feat][elem],
// so each lane holds 4 consecutive feats of its own element -> epilogue is
// ushort4 LDS stores (12 instead of 48 scalar b16), float4 out stores, float4
// bias loads. Product order per output element is identical to the previous
// kernel -> bit-identical results.
// Weights stream from d_ws (2.1 MB, L2-resident); each wave reads the full
// per-node weight set (4x per block vs cooperative version) -- absorbed by
// L1/L2, not HBM.

#define BT 64

typedef __attribute__((ext_vector_type(8))) short bf16x8;
typedef __attribute__((ext_vector_type(4))) float f32x4;
#define MFMA16 __builtin_amdgcn_mfma_f32_16x16x32_bf16

// ws layout (u16 units), per node i (stride 33792):
//   W1' [3][64 n][96 k]  @ 0      (k 0..63 parents, 64..79 exo, 80..95 zero)
//   W2' [3][64 n][64 k]  @ 18432
//   W3' [3][16 n][64 k]  @ 30720
#define NODE_STRIDE 33792
#define W1_SPLIT    6144
#define W2_OFF      18432
#define W2_SPLIT    4096
#define W3_OFF      30720
#define W3_SPLIT    1024

__device__ inline unsigned short bf16_rne(float x) {
    unsigned u = __float_as_uint(x);
    u += 0x7fffu + ((u >> 16) & 1u);
    return (unsigned short)(u >> 16);
}
__device__ inline float bf16_tof(unsigned short h) {
    return __uint_as_float(((unsigned)h) << 16);
}
__device__ inline void split3(float x, unsigned short& h, unsigned short& m,
                              unsigned short& l) {
    h = bf16_rne(x);
    float r = x - bf16_tof(h);      // exact (Sterbenz)
    m = bf16_rne(r);
    float r2 = r - bf16_tof(m);     // exact
    l = bf16_rne(r2);
}

// ---------------- prep: split weights into ws (unchanged) ----------------
#define PER_NODE_ITEMS (64 * 96 + 64 * 64 + 16 * 64)  // 11264

__global__ void prep_weights(const float* __restrict__ w_r1,
                             const float* __restrict__ w_r2,
                             const float* __restrict__ w_r3,
                             const float* __restrict__ w_i1,
                             const float* __restrict__ w_i2,
                             const float* __restrict__ w_i3,
                             unsigned short* __restrict__ ws) {
    int tid = blockIdx.x * 256 + threadIdx.x;
    if (tid >= 32 * PER_NODE_ITEMS) return;
    int node = tid / PER_NODE_ITEMS;
    int r = tid - node * PER_NODE_ITEMS;
    int off, stride;
    float wv = 0.0f;
    if (r < 6144) {                       // W1': n,k in [64][96]
        int n = r / 96, k = r - n * 96;
        if (k < 64) {
            wv = (node >= 4) ? w_i1[((node - 4) * 80 + k) * 64 + n] : 0.0f;
        } else if (k < 80) {
            wv = (node < 4) ? w_r1[(node * 16 + (k - 64)) * 64 + n]
                            : w_i1[((node - 4) * 80 + k) * 64 + n];
        } // else zero pad
        off = n * 96 + k; stride = W1_SPLIT;
    } else if (r < 10240) {               // W2': [64][64]
        int r2 = r - 6144;
        int n = r2 >> 6, k = r2 & 63;
        wv = (node < 4) ? w_r2[(node * 64 + k) * 64 + n]
                        : w_i2[((node - 4) * 64 + k) * 64 + n];
        off = W2_OFF + n * 64 + k; stride = W2_SPLIT;
    } else {                              // W3': [16][64]
        int r3 = r - 10240;
        int n = r3 >> 6, k = r3 & 63;
        wv = (node < 4) ? w_r3[(node * 64 + k) * 16 + n]
                        : w_i3[((node - 4) * 64 + k) * 16 + n];
        off = W3_OFF + n * 64 + k; stride = W3_SPLIT;
    }
    unsigned short h, m, l;
    split3(wv, h, m, l);
    unsigned short* base = ws + node * NODE_STRIDE;
    base[off] = h;
    base[off + stride] = m;
    base[off + 2 * stride] = l;
}

// ---------------- main kernel ----------------
__global__ __launch_bounds__(256, 2) void ncm_mfma(
    const float* __restrict__ u,
    const unsigned short* __restrict__ ws,
    const float* __restrict__ b_r1, const float* __restrict__ b_r2,
    const float* __restrict__ b_r3, const float* __restrict__ b_i1,
    const float* __restrict__ b_i2, const float* __restrict__ b_i3,
    float* __restrict__ out)
{
    // Per-wave private slices: [wave][...]. All access is intra-wave.
    __shared__ __align__(16) unsigned short ring[4][4][16][24]; // [w][slot][elem][feat]
    __shared__ __align__(16) unsigned short xu[4][3][16][32];   // [w][split][elem][feat] (16..31 zero)
    __shared__ __align__(16) unsigned short h1s[4][3][16][72];  // [w][split][elem][feat]
    __shared__ __align__(16) unsigned short h2s[4][3][16][72];

    const int tid = threadIdx.x;
    const int l   = tid & 63;
    const int w   = tid >> 6;     // wave 0..3
    const int lr  = l & 15;       // elem row within wave tile / frag row-col
    const int lq  = l >> 4;       // quad 0..3 (k-slice / feat group)

    // per-wave zero init (no cross-wave visibility needed -> no barrier)
    for (int z = l; z < 4 * 16 * 24; z += 64) ((unsigned short*)ring[w])[z] = 0;
    for (int z = l; z < 3 * 16 * 32; z += 64) ((unsigned short*)xu[w])[z] = 0;
    __builtin_amdgcn_wave_barrier();

    const long eg   = (long)blockIdx.x * BT;
    const long erow = eg + w * 16 + lr;          // this lane's batch element
    const float* u_row   = u   + erow * 512;
    float*       out_row = out + erow * 512;

    for (int i = 0; i < 32; ++i) {
        const unsigned short* Wn = ws + i * NODE_STRIDE;

        // ---- stage exo: feats lq*4..+3 of this lane's element ----
        {
            float4 uv = *(const float4*)(u_row + i * 16 + lq * 4);
            unsigned short h0, m0, l0, h1, m1, l1, h2, m2, l2, h3, m3, l3;
            split3(uv.x, h0, m0, l0); split3(uv.y, h1, m1, l1);
            split3(uv.z, h2, m2, l2); split3(uv.w, h3, m3, l3);
            *(ushort4*)&xu[w][0][lr][lq * 4] = make_ushort4(h0, h1, h2, h3);
            *(ushort4*)&xu[w][1][lr][lq * 4] = make_ushort4(m0, m1, m2, m3);
            *(ushort4*)&xu[w][2][lr][lq * 4] = make_ushort4(l0, l1, l2, l3);
        }
        __builtin_amdgcn_wave_barrier();

        f32x4 acc[4] = {{0,0,0,0},{0,0,0,0},{0,0,0,0},{0,0,0,0}};

        // ======== L1: D[feat][elem], acc[ft] covers feats ft*16..+15 ========
        if (i >= 4) {
            #pragma unroll
            for (int k0 = 0; k0 < 64; k0 += 32) {
                const int f = k0 + lq * 8;
                const int slot = (i + (f >> 4)) & 3;   // ring slot of that parent
                bf16x8 ab = *(const bf16x8*)&ring[w][slot][lr][f & 15];
                #pragma unroll
                for (int ft = 0; ft < 4; ++ft) {
                    const unsigned short* wp = Wn + (ft * 16 + lr) * 96 + f;
                    bf16x8 wb0 = *(const bf16x8*)(wp);
                    bf16x8 wb1 = *(const bf16x8*)(wp + W1_SPLIT);
                    bf16x8 wb2 = *(const bf16x8*)(wp + 2 * W1_SPLIT);
                    acc[ft] = MFMA16(wb0, ab, acc[ft], 0, 0, 0);
                    acc[ft] = MFMA16(wb1, ab, acc[ft], 0, 0, 0);
                    acc[ft] = MFMA16(wb2, ab, acc[ft], 0, 0, 0);
                }
            }
        }
        {   // exo region: A = W cols 64..95, B = xu feats 0..31 (16..31 zero)
            const int f = lq * 8;
            bf16x8 a0 = *(const bf16x8*)&xu[w][0][lr][f];
            bf16x8 a1 = *(const bf16x8*)&xu[w][1][lr][f];
            bf16x8 a2 = *(const bf16x8*)&xu[w][2][lr][f];
            #pragma unroll
            for (int ft = 0; ft < 4; ++ft) {
                const unsigned short* wp = Wn + (ft * 16 + lr) * 96 + 64 + f;
                bf16x8 wb0 = *(const bf16x8*)(wp);
                bf16x8 wb1 = *(const bf16x8*)(wp + W1_SPLIT);
                bf16x8 wb2 = *(const bf16x8*)(wp + 2 * W1_SPLIT);
                acc[ft] = MFMA16(wb0, a0, acc[ft], 0, 0, 0);
                acc[ft] = MFMA16(wb1, a0, acc[ft], 0, 0, 0);
                acc[ft] = MFMA16(wb2, a0, acc[ft], 0, 0, 0);
                acc[ft] = MFMA16(wb0, a1, acc[ft], 0, 0, 0);
                acc[ft] = MFMA16(wb1, a1, acc[ft], 0, 0, 0);
                acc[ft] = MFMA16(wb2, a1, acc[ft], 0, 0, 0);
                acc[ft] = MFMA16(wb0, a2, acc[ft], 0, 0, 0);
                acc[ft] = MFMA16(wb1, a2, acc[ft], 0, 0, 0);
            }
        }
        {   // L1 epilogue: lane holds feats ft*16+lq*4..+3 of elem lr
            const float* B1 = (i < 4) ? (b_r1 + i * 64) : (b_i1 + (i - 4) * 64);
            #pragma unroll
            for (int ft = 0; ft < 4; ++ft) {
                float4 bv = *(const float4*)(B1 + ft * 16 + lq * 4);
                float v0 = fmaxf(acc[ft][0] + bv.x, 0.0f);
                float v1 = fmaxf(acc[ft][1] + bv.y, 0.0f);
                float v2 = fmaxf(acc[ft][2] + bv.z, 0.0f);
                float v3 = fmaxf(acc[ft][3] + bv.w, 0.0f);
                unsigned short h0, m0, l0, h1, m1, l1, h2, m2, l2, h3, m3, l3;
                split3(v0, h0, m0, l0); split3(v1, h1, m1, l1);
                split3(v2, h2, m2, l2); split3(v3, h3, m3, l3);
                const int o = ft * 16 + lq * 4;
                *(ushort4*)&h1s[w][0][lr][o] = make_ushort4(h0, h1, h2, h3);
                *(ushort4*)&h1s[w][1][lr][o] = make_ushort4(m0, m1, m2, m3);
                *(ushort4*)&h1s[w][2][lr][o] = make_ushort4(l0, l1, l2, l3);
            }
        }
        __builtin_amdgcn_wave_barrier();

        // ======== L2: K = 64 from h1s ========
        #pragma unroll
        for (int ft = 0; ft < 4; ++ft) acc[ft] = (f32x4){0, 0, 0, 0};
        {
            const unsigned short* W2 = Wn + W2_OFF;
            #pragma unroll
            for (int k0 = 0; k0 < 64; k0 += 32) {
                const int f = k0 + lq * 8;
                bf16x8 a0 = *(const bf16x8*)&h1s[w][0][lr][f];
                bf16x8 a1 = *(const bf16x8*)&h1s[w][1][lr][f];
                bf16x8 a2 = *(const bf16x8*)&h1s[w][2][lr][f];
                #pragma unroll
                for (int ft = 0; ft < 4; ++ft) {
                    const unsigned short* wp = W2 + (ft * 16 + lr) * 64 + f;
                    bf16x8 wb0 = *(const bf16x8*)(wp);
                    bf16x8 wb1 = *(const bf16x8*)(wp + W2_SPLIT);
                    bf16x8 wb2 = *(const bf16x8*)(wp + 2 * W2_SPLIT);
                    acc[ft] = MFMA16(wb0, a0, acc[ft], 0, 0, 0);
                    acc[ft] = MFMA16(wb1, a0, acc[ft], 0, 0, 0);
                    acc[ft] = MFMA16(wb2, a0, acc[ft], 0, 0, 0);
                    acc[ft] = MFMA16(wb0, a1, acc[ft], 0, 0, 0);
                    acc[ft] = MFMA16(wb1, a1, acc[ft], 0, 0, 0);
                    acc[ft] = MFMA16(wb2, a1, acc[ft], 0, 0, 0);
                    acc[ft] = MFMA16(wb0, a2, acc[ft], 0, 0, 0);
                    acc[ft] = MFMA16(wb1, a2, acc[ft], 0, 0, 0);
                }
            }
        }
        {   // L2 epilogue
            const float* B2 = (i < 4) ? (b_r2 + i * 64) : (b_i2 + (i - 4) * 64);
            #pragma unroll
            for (int ft = 0; ft < 4; ++ft) {
                float4 bv = *(const float4*)(B2 + ft * 16 + lq * 4);
                float v0 = fmaxf(acc[ft][0] + bv.x, 0.0f);
                float v1 = fmaxf(acc[ft][1] + bv.y, 0.0f);
                float v2 = fmaxf(acc[ft][2] + bv.z, 0.0f);
                float v3 = fmaxf(acc[ft][3] + bv.w, 0.0f);
                unsigned short h0, m0, l0, h1, m1, l1, h2, m2, l2, h3, m3, l3;
                split3(v0, h0, m0, l0); split3(v1, h1, m1, l1);
                split3(v2, h2, m2, l2); split3(v3, h3, m3, l3);
                const int o = ft * 16 + lq * 4;
                *(ushort4*)&h2s[w][0][lr][o] = make_ushort4(h0, h1, h2, h3);
                *(ushort4*)&h2s[w][1][lr][o] = make_ushort4(m0, m1, m2, m3);
                *(ushort4*)&h2s[w][2][lr][o] = make_ushort4(l0, l1, l2, l3);
            }
        }
        __builtin_amdgcn_wave_barrier();

        // ======== L3: 16 feats (1 tile), K = 64 from h2s ========
        {
            f32x4 c3 = {0, 0, 0, 0};
            const unsigned short* W3 = Wn + W3_OFF;
            #pragma unroll
            for (int k0 = 0; k0 < 64; k0 += 32) {
                const int f = k0 + lq * 8;
                bf16x8 a0 = *(const bf16x8*)&h2s[w][0][lr][f];
                bf16x8 a1 = *(const bf16x8*)&h2s[w][1][lr][f];
                bf16x8 a2 = *(const bf16x8*)&h2s[w][2][lr][f];
                const unsigned short* wp = W3 + lr * 64 + f;
                bf16x8 wb0 = *(const bf16x8*)(wp);
                bf16x8 wb1 = *(const bf16x8*)(wp + W3_SPLIT);
                bf16x8 wb2 = *(const bf16x8*)(wp + 2 * W3_SPLIT);
                c3 = MFMA16(wb0, a0, c3, 0, 0, 0);
                c3 = MFMA16(wb1, a0, c3, 0, 0, 0);
                c3 = MFMA16(wb2, a0, c3, 0, 0, 0);
                c3 = MFMA16(wb0, a1, c3, 0, 0, 0);
                c3 = MFMA16(wb1, a1, c3, 0, 0, 0);
                c3 = MFMA16(wb2, a1, c3, 0, 0, 0);
                c3 = MFMA16(wb0, a2, c3, 0, 0, 0);
                c3 = MFMA16(wb1, a2, c3, 0, 0, 0);
            }
            const float* B3 = (i < 4) ? (b_r3 + i * 16) : (b_i3 + (i - 4) * 16);
            float4 bv = *(const float4*)(B3 + lq * 4);
            float v0 = c3[0] + bv.x;
            float v1 = c3[1] + bv.y;
            float v2 = c3[2] + bv.z;
            float v3 = c3[3] + bv.w;
            *(float4*)(out_row + i * 16 + lq * 4) = make_float4(v0, v1, v2, v3);
            const int slot = i & 3;
            *(ushort4*)&ring[w][slot][lr][lq * 4] = make_ushort4(
                v0 > 0.5f ? (unsigned short)0x3F80 : (unsigned short)0,
                v1 > 0.5f ? (unsigned short)0x3F80 : (unsigned short)0,
                v2 > 0.5f ? (unsigned short)0x3F80 : (unsigned short)0,
                v3 > 0.5f ? (unsigned short)0x3F80 : (unsigned short)0);
        }
        __builtin_amdgcn_wave_barrier();
    }
}

extern "C" void kernel_launch(void* const* d_in, const int* in_sizes, int n_in,
                              void* d_out, int out_size, void* d_ws, size_t ws_size,
                              hipStream_t stream) {
    const float* u    = (const float*)d_in[0];
    const float* w_r1 = (const float*)d_in[1];
    const float* b_r1 = (const float*)d_in[2];
    const float* w_r2 = (const float*)d_in[3];
    const float* b_r2 = (const float*)d_in[4];
    const float* w_r3 = (const float*)d_in[5];
    const float* b_r3 = (const float*)d_in[6];
    const float* w_i1 = (const float*)d_in[7];
    const float* b_i1 = (const float*)d_in[8];
    const float* w_i2 = (const float*)d_in[9];
    const float* b_i2 = (const float*)d_in[10];
    const float* w_i3 = (const float*)d_in[11];
    const float* b_i3 = (const float*)d_in[12];
    float* out = (float*)d_out;
    unsigned short* ws = (unsigned short*)d_ws;

    prep_weights<<<dim3((32 * PER_NODE_ITEMS) / 256), dim3(256), 0, stream>>>(
        w_r1, w_r2, w_r3, w_i1, w_i2, w_i3, ws);

    ncm_mfma<<<dim3(512), dim3(256), 0, stream>>>(
        u, ws, b_r1, b_r2, b_r3, b_i1, b_i2, b_i3, out);
}

// Round 3
// 352.526 us; speedup vs baseline: 1.3908x; 1.3908x over previous
//
#include <hip/hip_runtime.h>

// NCM via bf16-split MFMA — cooperative tiling (proven 243us base) + three
// reuse-preserving upgrades:
//  (1) swapped MFMA operands: D = W·X^T = [feat][elem]. A/B frags share the
//      per-lane layout, so all loads are byte-identical to the base kernel;
//      only the D interpretation changes -> lane holds 4 consecutive feats of
//      one elem -> uint2/float4 epilogues (12 LDS stores/node vs 48 scalar).
//  (2) packed split3 via v_cvt_pk_bf16_f32 (RNE, == bit-trick for finite):
//      11 VALU per 2 values vs ~26, and results land pre-packed for stores.
//  (3) exo inputs read directly from global by the consuming lane (no xu LDS
//      buffer, no staging pass, 3 barriers/node instead of 4). u re-read 4x
//      through L1/L2; HBM unchanged.
// h1s/h2s: unpadded 128B rows + XOR chunk-swizzle by (e&7): hottest ds_read
// pattern ~8-way -> 2-way.
// MFMA sequence per accumulator element identical to base -> bit-identical.

#define BT 64

typedef __attribute__((ext_vector_type(8))) short bf16x8;
typedef __attribute__((ext_vector_type(4))) float f32x4;
typedef __attribute__((ext_vector_type(4))) unsigned int u32x4;
#define MFMA16 __builtin_amdgcn_mfma_f32_16x16x32_bf16

// ws layout (u16 units), per node i (stride 33792):
//   W1' [3][64 n][96 k]  @ 0      (k 0..63 parents, 64..79 exo, 80..95 zero)
//   W2' [3][64 n][64 k]  @ 18432
//   W3' [3][16 n][64 k]  @ 30720
#define NODE_STRIDE 33792
#define W1_SPLIT    6144
#define W2_OFF      18432
#define W2_SPLIT    4096
#define W3_OFF      30720
#define W3_SPLIT    1024

__device__ inline unsigned short bf16_rne(float x) {
    unsigned u = __float_as_uint(x);
    u += 0x7fffu + ((u >> 16) & 1u);
    return (unsigned short)(u >> 16);
}
__device__ inline float bf16_tof(unsigned short h) {
    return __uint_as_float(((unsigned)h) << 16);
}
__device__ inline void split3(float x, unsigned short& h, unsigned short& m,
                              unsigned short& l) {
    h = bf16_rne(x);
    float r = x - bf16_tof(h);      // exact (Sterbenz)
    m = bf16_rne(r);
    float r2 = r - bf16_tof(m);     // exact
    l = bf16_rne(r2);
}

// Packed pair split: v_cvt_pk_bf16_f32 is RNE (default MODE) == bf16_rne for
// all finite inputs. D.lo = bf16(a), D.hi = bf16(b).
__device__ inline unsigned cvt_pk_bf16(float a, float b) {
    unsigned d;
    asm("v_cvt_pk_bf16_f32 %0, %1, %2" : "=v"(d) : "v"(a), "v"(b));
    return d;
}
__device__ inline void split3_pair(float a, float b,
                                   unsigned& h, unsigned& m, unsigned& l) {
    h = cvt_pk_bf16(a, b);
    float ra = a - __uint_as_float(h << 16);          // exact
    float rb = b - __uint_as_float(h & 0xffff0000u);  // exact
    m = cvt_pk_bf16(ra, rb);
    float sa = ra - __uint_as_float(m << 16);         // exact
    float sb = rb - __uint_as_float(m & 0xffff0000u); // exact
    l = cvt_pk_bf16(sa, sb);
}

// XOR chunk-swizzle for h buffers: 128B row = 8 chunks of 16B; physical
// chunk = logical chunk ^ (e&7). feat in u16 units; returns u16 index in row.
__device__ inline int hswz(int e, int feat) {
    return (feat & 7) | ((((feat >> 3) ^ e) & 7) << 3);
}

// ---------------- prep: split weights into ws (unchanged) ----------------
#define PER_NODE_ITEMS (64 * 96 + 64 * 64 + 16 * 64)  // 11264

__global__ void prep_weights(const float* __restrict__ w_r1,
                             const float* __restrict__ w_r2,
                             const float* __restrict__ w_r3,
                             const float* __restrict__ w_i1,
                             const float* __restrict__ w_i2,
                             const float* __restrict__ w_i3,
                             unsigned short* __restrict__ ws) {
    int tid = blockIdx.x * 256 + threadIdx.x;
    if (tid >= 32 * PER_NODE_ITEMS) return;
    int node = tid / PER_NODE_ITEMS;
    int r = tid - node * PER_NODE_ITEMS;
    int off, stride;
    float wv = 0.0f;
    if (r < 6144) {                       // W1': n,k in [64][96]
        int n = r / 96, k = r - n * 96;
        if (k < 64) {
            wv = (node >= 4) ? w_i1[((node - 4) * 80 + k) * 64 + n] : 0.0f;
        } else if (k < 80) {
            wv = (node < 4) ? w_r1[(node * 16 + (k - 64)) * 64 + n]
                            : w_i1[((node - 4) * 80 + k) * 64 + n];
        } // else zero pad
        off = n * 96 + k; stride = W1_SPLIT;
    } else if (r < 10240) {               // W2': [64][64]
        int r2 = r - 6144;
        int n = r2 >> 6, k = r2 & 63;
        wv = (node < 4) ? w_r2[(node * 64 + k) * 64 + n]
                        : w_i2[((node - 4) * 64 + k) * 64 + n];
        off = W2_OFF + n * 64 + k; stride = W2_SPLIT;
    } else {                              // W3': [16][64]
        int r3 = r - 10240;
        int n = r3 >> 6, k = r3 & 63;
        wv = (node < 4) ? w_r3[(node * 64 + k) * 16 + n]
                        : w_i3[((node - 4) * 64 + k) * 16 + n];
        off = W3_OFF + n * 64 + k; stride = W3_SPLIT;
    }
    unsigned short h, m, l;
    split3(wv, h, m, l);
    unsigned short* base = ws + node * NODE_STRIDE;
    base[off] = h;
    base[off + stride] = m;
    base[off + 2 * stride] = l;
}

// ---------------- main kernel ----------------
__global__ __launch_bounds__(256, 2) void ncm_mfma(
    const float* __restrict__ u,
    const unsigned short* __restrict__ ws,
    const float* __restrict__ b_r1, const float* __restrict__ b_r2,
    const float* __restrict__ b_r3, const float* __restrict__ b_i1,
    const float* __restrict__ b_i2, const float* __restrict__ b_i3,
    float* __restrict__ out)
{
    __shared__ __align__(16) unsigned short ring[4][64][24]; // parent bits
    __shared__ __align__(16) unsigned short h1s[3][64][64];  // [split][elem][feat-swz]
    __shared__ __align__(16) unsigned short h2s[3][64][64];

    const int tid = threadIdx.x;
    const int l   = tid & 63;
    const int w   = tid >> 6;     // wave 0..3
    const int lr  = l & 15;       // frag row/col index
    const int lq  = l >> 4;       // quad 0..3 (k-slice / feat sub-group)
    const int n1  = 16 * w + lr;  // this wave's weight row (out feat), L1/L2

    const long eg = (long)blockIdx.x * BT;

    // ring needs no init: node i>=4 reads slots of parents i-4..i-1, all
    // written by earlier L3 phases before first read.

    for (int i = 0; i < 32; ++i) {
        const unsigned short* Wn = ws + i * NODE_STRIDE;
        f32x4 acc[4] = {{0,0,0,0},{0,0,0,0},{0,0,0,0},{0,0,0,0}};

        // ======== L1: D[feat][elem]; acc[m] = elems m*16..+15 ========
        if (i >= 4) {   // parent region, K = 64 (4 parents x 16)
            #pragma unroll
            for (int k0 = 0; k0 < 64; k0 += 32) {
                const int f = k0 + lq * 8;
                const int slot = (i + (f >> 4)) & 3;   // ring slot of parent
                const unsigned short* wp = Wn + n1 * 96 + f;
                bf16x8 wb0 = *(const bf16x8*)(wp);
                bf16x8 wb1 = *(const bf16x8*)(wp + W1_SPLIT);
                bf16x8 wb2 = *(const bf16x8*)(wp + 2 * W1_SPLIT);
                #pragma unroll
                for (int m = 0; m < 4; ++m) {
                    bf16x8 ab = *(const bf16x8*)&ring[slot][m * 16 + lr][f & 15];
                    acc[m] = MFMA16(wb0, ab, acc[m], 0, 0, 0);
                    acc[m] = MFMA16(wb1, ab, acc[m], 0, 0, 0);
                    acc[m] = MFMA16(wb2, ab, acc[m], 0, 0, 0);
                }
            }
        }
        {   // exo region: B-frag k 0..15 real (lq<2), 16..31 zero (lq>=2)
            const unsigned short* wp = Wn + n1 * 96 + 64 + lq * 8;
            bf16x8 wb0 = *(const bf16x8*)(wp);
            bf16x8 wb1 = *(const bf16x8*)(wp + W1_SPLIT);
            bf16x8 wb2 = *(const bf16x8*)(wp + 2 * W1_SPLIT);
            #pragma unroll
            for (int m = 0; m < 4; ++m) {
                bf16x8 a0 = {}, a1 = {}, a2 = {};
                if (lq < 2) {
                    const float* up =
                        u + (eg + m * 16 + lr) * 512 + i * 16 + lq * 8;
                    float4 p = *(const float4*)up;
                    float4 q = *(const float4*)(up + 4);
                    unsigned hA,mA,lA,hB,mB,lB,hC,mC,lC,hD,mD,lD;
                    split3_pair(p.x, p.y, hA, mA, lA);
                    split3_pair(p.z, p.w, hB, mB, lB);
                    split3_pair(q.x, q.y, hC, mC, lC);
                    split3_pair(q.z, q.w, hD, mD, lD);
                    a0 = __builtin_bit_cast(bf16x8, (u32x4){hA, hB, hC, hD});
                    a1 = __builtin_bit_cast(bf16x8, (u32x4){mA, mB, mC, mD});
                    a2 = __builtin_bit_cast(bf16x8, (u32x4){lA, lB, lC, lD});
                }
                acc[m] = MFMA16(wb0, a0, acc[m], 0, 0, 0);
                acc[m] = MFMA16(wb1, a0, acc[m], 0, 0, 0);
                acc[m] = MFMA16(wb2, a0, acc[m], 0, 0, 0);
                acc[m] = MFMA16(wb0, a1, acc[m], 0, 0, 0);
                acc[m] = MFMA16(wb1, a1, acc[m], 0, 0, 0);
                acc[m] = MFMA16(wb2, a1, acc[m], 0, 0, 0);
                acc[m] = MFMA16(wb0, a2, acc[m], 0, 0, 0);
                acc[m] = MFMA16(wb1, a2, acc[m], 0, 0, 0);
            }
        }
        {   // L1 epilogue: lane holds feats 16w+4lq..+3 of elem m*16+lr
            const float* B1 = (i < 4) ? (b_r1 + i * 64) : (b_i1 + (i - 4) * 64);
            float4 bv = *(const float4*)(B1 + 16 * w + 4 * lq);
            const int fo = 16 * w + 4 * lq;
            #pragma unroll
            for (int m = 0; m < 4; ++m) {
                const int e = m * 16 + lr;
                float v0 = fmaxf(acc[m][0] + bv.x, 0.0f);
                float v1 = fmaxf(acc[m][1] + bv.y, 0.0f);
                float v2 = fmaxf(acc[m][2] + bv.z, 0.0f);
                float v3 = fmaxf(acc[m][3] + bv.w, 0.0f);
                unsigned hP0, mP0, lP0, hP1, mP1, lP1;
                split3_pair(v0, v1, hP0, mP0, lP0);
                split3_pair(v2, v3, hP1, mP1, lP1);
                const int o = hswz(e, fo);
                *(uint2*)&h1s[0][e][o] = make_uint2(hP0, hP1);
                *(uint2*)&h1s[1][e][o] = make_uint2(mP0, mP1);
                *(uint2*)&h1s[2][e][o] = make_uint2(lP0, lP1);
            }
        }
        __syncthreads();   // B1: h1s complete

        // ======== L2: K = 64 from h1s ========
        #pragma unroll
        for (int m = 0; m < 4; ++m) acc[m] = (f32x4){0, 0, 0, 0};
        {
            const unsigned short* W2 = Wn + W2_OFF;
            #pragma unroll
            for (int k0 = 0; k0 < 64; k0 += 32) {
                const int f = k0 + lq * 8;
                const unsigned short* wp = W2 + n1 * 64 + f;
                bf16x8 wb0 = *(const bf16x8*)(wp);
                bf16x8 wb1 = *(const bf16x8*)(wp + W2_SPLIT);
                bf16x8 wb2 = *(const bf16x8*)(wp + 2 * W2_SPLIT);
                #pragma unroll
                for (int m = 0; m < 4; ++m) {
                    const int e = m * 16 + lr;
                    const int o = hswz(e, f);
                    bf16x8 a0 = *(const bf16x8*)&h1s[0][e][o];
                    bf16x8 a1 = *(const bf16x8*)&h1s[1][e][o];
                    bf16x8 a2 = *(const bf16x8*)&h1s[2][e][o];
                    acc[m] = MFMA16(wb0, a0, acc[m], 0, 0, 0);
                    acc[m] = MFMA16(wb1, a0, acc[m], 0, 0, 0);
                    acc[m] = MFMA16(wb2, a0, acc[m], 0, 0, 0);
                    acc[m] = MFMA16(wb0, a1, acc[m], 0, 0, 0);
                    acc[m] = MFMA16(wb1, a1, acc[m], 0, 0, 0);
                    acc[m] = MFMA16(wb2, a1, acc[m], 0, 0, 0);
                    acc[m] = MFMA16(wb0, a2, acc[m], 0, 0, 0);
                    acc[m] = MFMA16(wb1, a2, acc[m], 0, 0, 0);
                }
            }
        }
        {   // L2 epilogue
            const float* B2 = (i < 4) ? (b_r2 + i * 64) : (b_i2 + (i - 4) * 64);
            float4 bv = *(const float4*)(B2 + 16 * w + 4 * lq);
            const int fo = 16 * w + 4 * lq;
            #pragma unroll
            for (int m = 0; m < 4; ++m) {
                const int e = m * 16 + lr;
                float v0 = fmaxf(acc[m][0] + bv.x, 0.0f);
                float v1 = fmaxf(acc[m][1] + bv.y, 0.0f);
                float v2 = fmaxf(acc[m][2] + bv.z, 0.0f);
                float v3 = fmaxf(acc[m][3] + bv.w, 0.0f);
                unsigned hP0, mP0, lP0, hP1, mP1, lP1;
                split3_pair(v0, v1, hP0, mP0, lP0);
                split3_pair(v2, v3, hP1, mP1, lP1);
                const int o = hswz(e, fo);
                *(uint2*)&h2s[0][e][o] = make_uint2(hP0, hP1);
                *(uint2*)&h2s[1][e][o] = make_uint2(mP0, mP1);
                *(uint2*)&h2s[2][e][o] = make_uint2(lP0, lP1);
            }
        }
        __syncthreads();   // B2: h2s complete

        // ======== L3: wave = M-tile (elems 16w..+15), 16 feats ========
        {
            f32x4 c3 = {0, 0, 0, 0};
            const unsigned short* W3 = Wn + W3_OFF;
            const int e = 16 * w + lr;
            #pragma unroll
            for (int k0 = 0; k0 < 64; k0 += 32) {
                const int f = k0 + lq * 8;
                const unsigned short* wp = W3 + lr * 64 + f;
                bf16x8 wb0 = *(const bf16x8*)(wp);
                bf16x8 wb1 = *(const bf16x8*)(wp + W3_SPLIT);
                bf16x8 wb2 = *(const bf16x8*)(wp + 2 * W3_SPLIT);
                const int o = hswz(e, f);
                bf16x8 a0 = *(const bf16x8*)&h2s[0][e][o];
                bf16x8 a1 = *(const bf16x8*)&h2s[1][e][o];
                bf16x8 a2 = *(const bf16x8*)&h2s[2][e][o];
                c3 = MFMA16(wb0, a0, c3, 0, 0, 0);
                c3 = MFMA16(wb1, a0, c3, 0, 0, 0);
                c3 = MFMA16(wb2, a0, c3, 0, 0, 0);
                c3 = MFMA16(wb0, a1, c3, 0, 0, 0);
                c3 = MFMA16(wb1, a1, c3, 0, 0, 0);
                c3 = MFMA16(wb2, a1, c3, 0, 0, 0);
                c3 = MFMA16(wb0, a2, c3, 0, 0, 0);
                c3 = MFMA16(wb1, a2, c3, 0, 0, 0);
            }
            const float* B3 = (i < 4) ? (b_r3 + i * 16) : (b_i3 + (i - 4) * 16);
            float4 bv = *(const float4*)(B3 + 4 * lq);
            float v0 = c3[0] + bv.x;
            float v1 = c3[1] + bv.y;
            float v2 = c3[2] + bv.z;
            float v3 = c3[3] + bv.w;
            *(float4*)(out + (eg + e) * 512 + i * 16 + 4 * lq) =
                make_float4(v0, v1, v2, v3);
            const int slot = i & 3;
            unsigned r0 = (v0 > 0.5f ? 0x3F80u : 0u) |
                          ((v1 > 0.5f ? 0x3F80u : 0u) << 16);
            unsigned r1 = (v2 > 0.5f ? 0x3F80u : 0u) |
                          ((v3 > 0.5f ? 0x3F80u : 0u) << 16);
            *(uint2*)&ring[slot][e][4 * lq] = make_uint2(r0, r1);
        }
        __syncthreads();   // B3: ring visible; h buffers free for next node
    }
}

extern "C" void kernel_launch(void* const* d_in, const int* in_sizes, int n_in,
                              void* d_out, int out_size, void* d_ws, size_t ws_size,
                              hipStream_t stream) {
    const float* u    = (const float*)d_in[0];
    const float* w_r1 = (const float*)d_in[1];
    const float* b_r1 = (const float*)d_in[2];
    const float* w_r2 = (const float*)d_in[3];
    const float* b_r2 = (const float*)d_in[4];
    const float* w_r3 = (const float*)d_in[5];
    const float* b_r3 = (const float*)d_in[6];
    const float* w_i1 = (const float*)d_in[7];
    const float* b_i1 = (const float*)d_in[8];
    const float* w_i2 = (const float*)d_in[9];
    const float* b_i2 = (const float*)d_in[10];
    const float* w_i3 = (const float*)d_in[11];
    const float* b_i3 = (const float*)d_in[12];
    float* out = (float*)d_out;
    unsigned short* ws = (unsigned short*)d_ws;

    prep_weights<<<dim3((32 * PER_NODE_ITEMS) / 256), dim3(256), 0, stream>>>(
        w_r1, w_r2, w_r3, w_i1, w_i2, w_i3, ws);

    ncm_mfma<<<dim3(512), dim3(256), 0, stream>>>(
        u, ws, b_r1, b_r2, b_r3, b_i1, b_i2, b_i3, out);
}